// Round 14
// baseline (50.797 us; speedup 1.0000x reference)
//
#include <hip/hip_runtime.h>
#include <hip/hip_bf16.h>
#include <stdint.h>

typedef short bf16x8 __attribute__((ext_vector_type(8)));
typedef float f32x4  __attribute__((ext_vector_type(4)));

#define B_   32
#define CIN  32
#define COUT 64
#define H_   128
#define W_   128
#define HW   (H_ * W_)
#define WCOLS 66           // 64 px + 2 halo cols per wave tile
#define WROWS 3            // input rows per wave tile
#define WLDS  (WROWS * WCOLS * 32)   // ushorts per slice (12,672 B)
#define SCW  68            // scratch row stride in words
#define NBLK 8192          // 1 wave-tile per block

// s_waitcnt imm: vmcnt=63, expcnt=7, lgkmcnt=0  -> wait LDS only, NOT stores
#define WAIT_LGKM0() __builtin_amdgcn_s_waitcnt(0xC07F)

static __device__ __forceinline__ ushort f2bf(float v) {
    __hip_bfloat16 h = __float2bfloat16(v);
    return __builtin_bit_cast(ushort, h);
}

// ---------------------------------------------------------------------------
// Weight pack: [Cout][Cin][3][3] fp32 -> bf16 A-fragment order
// Wp[tap][ocg][lane][j] = W[ocg*16 + (lane&15)][8*(lane>>4)+j][ky][kx]
// ---------------------------------------------------------------------------
__global__ void prep_w_kernel(const float* __restrict__ wt, ushort* __restrict__ Wp) {
    int p = blockIdx.x * blockDim.x + threadIdx.x;
    if (p >= COUT * CIN * 9) return;  // 18432
    int j    = p & 7;
    int lane = (p >> 3) & 63;
    int g    = (p >> 9) & 3;
    int tap  = p >> 11;
    int oc   = g * 16 + (lane & 15);
    int cin  = (lane >> 4) * 8 + j;
    int ky   = tap / 3;
    int kx   = tap % 3;
    Wp[p] = f2bf(wt[(((size_t)oc * CIN + cin) * 3 + ky) * 3 + kx]);
}

// ---------------------------------------------------------------------------
// Wave-autonomous conv, 1 wave per block, ZERO barriers. Each wave stages
// its private 3x66-col patch (fp32 NCHW -> bf16 NHWC, XOR-swizzled) into
// its own 12.7KB LDS, lgkm-waits, 144 MFMAs, then the R12 epilogue: LDS
// transpose -> 256B-contiguous nontemporal dwordx4 (full lines, no RFO, no
// L3 pollution). 12 blocks/CU (LDS-capped) = 12 independent waves/CU that
// self-stagger -> continuous aggregate load/store issue (duty-cycle fix).
// ---------------------------------------------------------------------------
__global__ __launch_bounds__(64, 3) void conv_wave_kernel(
    const float* __restrict__ in, const ushort* __restrict__ Wp,
    float* __restrict__ out) {
    __shared__ ushort wlds[WLDS];   // 12,672 B (one wave's slice)

    int hw_blk  = blockIdx.x;
    int t = (hw_blk & 7) * (NBLK / 8) + (hw_blk >> 3);   // XCD swizzle, bijective
    int lane = threadIdx.x;
    int llo  = lane & 15;
    int lhi  = lane >> 4;

    int b   = t >> 8;                        // 256 tiles per image
    int h   = (t & 255) >> 1;                // output row
    int px0 = (t & 1) * 64;                  // px half

    const float* ib = in + (size_t)b * CIN * HW;

    // ---- stage: 3 rows x 66 cols; lanes = consecutive cols ----
#pragma unroll
    for (int r = 0; r < 3; ++r) {
        int gy  = h + r - 1;
        int pxg = px0 + lane - 1;
        bf16x8 v[4];
        if (gy >= 0 && gy < H_ && pxg >= 0 && pxg < W_) {
            const float* src = ib + (size_t)gy * W_ + pxg;
#pragma unroll
            for (int q = 0; q < 4; ++q)
#pragma unroll
                for (int j = 0; j < 8; ++j)
                    v[q][j] = (short)f2bf(src[(size_t)(q * 8 + j) * HW]);
        } else {
#pragma unroll
            for (int q = 0; q < 4; ++q)
#pragma unroll
                for (int j = 0; j < 8; ++j)
                    v[q][j] = 0;
        }
        uint32_t base = (uint32_t)(r * WCOLS + lane) * 64u;
        uint32_t sw = (((uint32_t)lane >> 1) & 3u) << 4;
#pragma unroll
        for (int q = 0; q < 4; ++q)
            *(bf16x8*)((char*)wlds + base + (((uint32_t)q << 4) ^ sw)) = v[q];
    }
    // tail: cols 64,65 of each row (6 columns, lanes 0..5)
    if (lane < 6) {
        int r   = lane >> 1;
        int lc  = 64 + (lane & 1);
        int gy  = h + r - 1;
        int pxg = px0 + lc - 1;
        bf16x8 v[4];
        if (gy >= 0 && gy < H_ && pxg >= 0 && pxg < W_) {
            const float* src = ib + (size_t)gy * W_ + pxg;
#pragma unroll
            for (int q = 0; q < 4; ++q)
#pragma unroll
                for (int j = 0; j < 8; ++j)
                    v[q][j] = (short)f2bf(src[(size_t)(q * 8 + j) * HW]);
        } else {
#pragma unroll
            for (int q = 0; q < 4; ++q)
#pragma unroll
                for (int j = 0; j < 8; ++j)
                    v[q][j] = 0;
        }
        uint32_t base = (uint32_t)(r * WCOLS + lc) * 64u;
        uint32_t sw = (((uint32_t)lc >> 1) & 3u) << 4;
#pragma unroll
        for (int q = 0; q < 4; ++q)
            *(bf16x8*)((char*)wlds + base + (((uint32_t)q << 4) ^ sw)) = v[q];
    }
    WAIT_LGKM0();   // own ds_writes visible to own ds_reads (no barrier)

    // ---- compute: 64 oc x 64 px ----
    f32x4 acc[4][4];
#pragma unroll
    for (int g = 0; g < 4; ++g)
#pragma unroll
        for (int nf = 0; nf < 4; ++nf) {
            acc[g][nf][0] = 0.f; acc[g][nf][1] = 0.f;
            acc[g][nf][2] = 0.f; acc[g][nf][3] = 0.f;
        }

#pragma unroll
    for (int tap = 0; tap < 9; ++tap) {
        int dy = tap / 3;
        int dx = tap % 3;
        bf16x8 Af[4];
#pragma unroll
        for (int g = 0; g < 4; ++g)
            Af[g] = *(const bf16x8*)(Wp + ((size_t)(tap * 4 + g) * 64 + lane) * 8);
#pragma unroll
        for (int nf = 0; nf < 4; ++nf) {
            int lc = nf * 16 + llo + dx;     // 0..65
            uint32_t byte = (uint32_t)(dy * WCOLS + lc) * 64u +
                            (((uint32_t)lhi << 4) ^ ((((uint32_t)lc >> 1) & 3u) << 4));
            bf16x8 Bf = *(const bf16x8*)((const char*)wlds + byte);
#pragma unroll
            for (int g = 0; g < 4; ++g)
                acc[g][nf] = __builtin_amdgcn_mfma_f32_16x16x32_bf16(Af[g], Bf, acc[g][nf], 0, 0, 0);
        }
    }

    // ---- epilogue: own slice dead -> scratch transpose -> nt full lines --
    float* myscr = (float*)wlds;
    float* obase = out + (size_t)b * COUT * HW + (size_t)h * W_ + px0;
#pragma unroll
    for (int g = 0; g < 4; ++g) {
#pragma unroll
        for (int nf = 0; nf < 4; ++nf)
#pragma unroll
            for (int r = 0; r < 4; ++r)
                myscr[(lhi * 4 + r) * SCW + nf * 16 + llo] = acc[g][nf][r];
        WAIT_LGKM0();
#pragma unroll
        for (int j = 0; j < 4; ++j) {
            int ocp = j * 4 + lhi;           // 0..15
            f32x4 vv = *(const f32x4*)(myscr + ocp * SCW + llo * 4);
            float* dst = obase + (size_t)(g * 16 + ocp) * HW + llo * 4;
#pragma unroll
            for (int k = 0; k < 4; ++k)
                __builtin_nontemporal_store(vv[k], dst + k);
        }
        WAIT_LGKM0();
    }
}

// ---------------------------------------------------------------------------
// Fallback: naive fp32 direct conv (only if workspace is too small for Wp)
// ---------------------------------------------------------------------------
__global__ void conv_naive_kernel(const float* __restrict__ in,
                                  const float* __restrict__ wt,
                                  float* __restrict__ out) {
    int idx = blockIdx.x * blockDim.x + threadIdx.x;
    if (idx >= B_ * COUT * HW) return;
    int w  = idx & 127;
    int h  = (idx >> 7) & 127;
    int oc = (idx >> 14) & 63;
    int b  = idx >> 20;
    float s = 0.f;
    for (int c = 0; c < CIN; ++c)
        for (int ky = 0; ky < 3; ++ky) {
            int y = h + ky - 1;
            if ((unsigned)y >= (unsigned)H_) continue;
            for (int kx = 0; kx < 3; ++kx) {
                int x = w + kx - 1;
                if ((unsigned)x >= (unsigned)W_) continue;
                s += in[((size_t)(b * CIN + c) * H_ + y) * W_ + x] *
                     wt[(((size_t)oc * CIN + c) * 3 + ky) * 3 + kx];
            }
        }
    out[idx] = s;
}

extern "C" void kernel_launch(void* const* d_in, const int* in_sizes, int n_in,
                              void* d_out, int out_size, void* d_ws, size_t ws_size,
                              hipStream_t stream) {
    const float* in = (const float*)d_in[0];
    const float* wt = (const float*)d_in[1];
    float* out = (float*)d_out;

    size_t Wp_bytes = (size_t)COUT * CIN * 9 * 2;   // 36,864

    if (ws_size >= Wp_bytes) {
        ushort* Wp = (ushort*)d_ws;
        prep_w_kernel<<<(COUT * CIN * 9 + 255) / 256, 256, 0, stream>>>(wt, Wp);
        conv_wave_kernel<<<NBLK, 64, 0, stream>>>(in, Wp, out);
    } else {
        int total = B_ * COUT * HW;
        conv_naive_kernel<<<(total + 255) / 256, 256, 0, stream>>>(in, wt, out);
    }
}

// Round 15
// 46.894 us; speedup vs baseline: 1.0832x; 1.0832x over previous
//
#include <hip/hip_runtime.h>
#include <hip/hip_bf16.h>
#include <stdint.h>

typedef short bf16x8 __attribute__((ext_vector_type(8)));
typedef float f32x4  __attribute__((ext_vector_type(4)));

#define B_   32
#define CIN  32
#define COUT 64
#define H_   128
#define W_   128
#define HW   (H_ * W_)
#define T_   2            // output rows per block
#define RROWS 4           // staged input rows = T_+2
#define PXW  130          // padded width
#define SCW  68           // scratch row stride in words (16B-aligned, 2-way banks)

// s_waitcnt imm: vmcnt=63, expcnt=7, lgkmcnt=0  -> wait LDS only, NOT stores
#define WAIT_LGKM0() __builtin_amdgcn_s_waitcnt(0xC07F)

static __device__ __forceinline__ ushort f2bf(float v) {
    __hip_bfloat16 h = __float2bfloat16(v);
    return __builtin_bit_cast(ushort, h);
}

// ---------------------------------------------------------------------------
// Weight pack: [Cout][Cin][3][3] fp32 -> bf16 A-fragment order
// Wp[tap][ocg][lane][j] = W[ocg*16 + (lane&15)][8*(lane>>4)+j][ky][kx]
// ---------------------------------------------------------------------------
__global__ void prep_w_kernel(const float* __restrict__ wt, ushort* __restrict__ Wp) {
    int p = blockIdx.x * blockDim.x + threadIdx.x;
    if (p >= COUT * CIN * 9) return;  // 18432
    int j    = p & 7;
    int lane = (p >> 3) & 63;
    int g    = (p >> 9) & 3;
    int tap  = p >> 11;
    int oc   = g * 16 + (lane & 15);
    int cin  = (lane >> 4) * 8 + j;
    int ky   = tap / 3;
    int kx   = tap % 3;
    Wp[p] = f2bf(wt[(((size_t)oc * CIN + cin) * 3 + ky) * 3 + kx]);
}

// ---------------------------------------------------------------------------
// R12 structure (best: 46.31us) with VECTOR nontemporal stores: the f32x4 is
// stored as ONE 16B nt store (guaranteed global_store_dwordx4 nt, 256B
// contiguous per instruction) instead of 4 scalar nt dwords that — if left
// unmerged — bypass the L2 write-combiner as 16B-stride fragments and
// throttle the HBM write stream to partial sectors.
// ---------------------------------------------------------------------------
__global__ __launch_bounds__(256, 3) void conv_fused_kernel(
    const float* __restrict__ in, const ushort* __restrict__ Wp,
    float* __restrict__ out) {
    __shared__ ushort lds[RROWS * PXW * 32];     // 33,280 B
    __shared__ float  scr[4][16 * SCW];          // 17,408 B (per-wave scratch)

    int hw_blk  = blockIdx.x;
    int logical = (hw_blk & 7) * 256 + (hw_blk >> 3);   // grid = 2048 = 8*256
    int b   = logical >> 6;          // /64
    int h0  = (logical & 63) * T_;
    int tid = threadIdx.x;

    // ---- stage: thread = one (row, px) column, loop 32 channels ----
    for (int i = tid; i < RROWS * PXW; i += 256) {
        int r  = i / PXW;
        int px = i - r * PXW;
        int gy = h0 + r - 1;
        bf16x8 v[4];
        if (gy >= 0 && gy < H_ && px >= 1 && px <= W_) {
            const float* src = in + ((size_t)b * CIN * H_ + gy) * W_ + (px - 1);
#pragma unroll
            for (int q = 0; q < 4; ++q)
#pragma unroll
                for (int j = 0; j < 8; ++j)
                    v[q][j] = (short)f2bf(src[(size_t)(q * 8 + j) * HW]);
        } else {
#pragma unroll
            for (int q = 0; q < 4; ++q)
#pragma unroll
                for (int j = 0; j < 8; ++j)
                    v[q][j] = 0;
        }
        uint32_t base_byte = (uint32_t)i * 64;
        uint32_t sw = ((uint32_t)(px >> 1) & 3u) << 4;
#pragma unroll
        for (int q = 0; q < 4; ++q)
            *(bf16x8*)((char*)lds + base_byte + (((uint32_t)q << 4) ^ sw)) = v[q];
    }
    __syncthreads();

    // ---- compute: wave = (row = wid>>1, px half = wid&1), 64 oc x 64 px ----
    int wid  = tid >> 6;
    int lane = tid & 63;
    int llo  = lane & 15;
    int lhi  = lane >> 4;
    int row  = wid >> 1;            // 0..1
    int px0  = (wid & 1) * 64;
    int h    = h0 + row;

    float* myscr = &scr[wid][0];
    float* obase = out + (size_t)b * COUT * HW + (size_t)h * W_ + px0;

#pragma unroll
    for (int p = 0; p < 2; ++p) {
        int gp = ((p + (wid & 1)) & 1) * 2;    // oc-half for this pass

        f32x4 acc[2][4];
#pragma unroll
        for (int gi = 0; gi < 2; ++gi)
#pragma unroll
            for (int nf = 0; nf < 4; ++nf) {
                acc[gi][nf][0] = 0.f; acc[gi][nf][1] = 0.f;
                acc[gi][nf][2] = 0.f; acc[gi][nf][3] = 0.f;
            }

#pragma unroll
        for (int tap = 0; tap < 9; ++tap) {
            int dy = tap / 3;
            int dx = tap % 3;
            int rbase = (row + dy) * PXW;
            bf16x8 Af[2];
#pragma unroll
            for (int gi = 0; gi < 2; ++gi)
                Af[gi] = *(const bf16x8*)(Wp + ((size_t)(tap * 4 + gp + gi) * 64 + lane) * 8);
#pragma unroll
            for (int nf = 0; nf < 4; ++nf) {
                int px = px0 + nf * 16 + llo + dx;
                uint32_t byte = (uint32_t)(rbase + px) * 64u +
                                (((uint32_t)lhi << 4) ^ ((((uint32_t)px >> 1) & 3u) << 4));
                bf16x8 Bf = *(const bf16x8*)((const char*)lds + byte);
#pragma unroll
                for (int gi = 0; gi < 2; ++gi)
                    acc[gi][nf] = __builtin_amdgcn_mfma_f32_16x16x32_bf16(Af[gi], Bf, acc[gi][nf], 0, 0, 0);
            }
        }

        // ---- store this oc-half (full-line VECTOR nt dwordx4 via scratch) --
#pragma unroll
        for (int gi = 0; gi < 2; ++gi) {
            int g = gp + gi;
#pragma unroll
            for (int nf = 0; nf < 4; ++nf)
#pragma unroll
                for (int r = 0; r < 4; ++r)
                    myscr[(lhi * 4 + r) * SCW + nf * 16 + llo] = acc[gi][nf][r];
            WAIT_LGKM0();                    // scratch writes visible (LDS only)
#pragma unroll
            for (int j = 0; j < 4; ++j) {
                int ocp = j * 4 + lhi;       // 0..15
                f32x4 vv = *(const f32x4*)(myscr + ocp * SCW + llo * 4);
                int oc = g * 16 + ocp;
                f32x4* dst = (f32x4*)(obase + (size_t)oc * HW + llo * 4);
                __builtin_nontemporal_store(vv, dst);   // ONE dwordx4 nt
            }
            WAIT_LGKM0();                    // LDS reads done before scratch overwrite
        }
    }
}

// ---------------------------------------------------------------------------
// Fallback: naive fp32 direct conv (only if workspace is too small for Wp)
// ---------------------------------------------------------------------------
__global__ void conv_naive_kernel(const float* __restrict__ in,
                                  const float* __restrict__ wt,
                                  float* __restrict__ out) {
    int idx = blockIdx.x * blockDim.x + threadIdx.x;
    if (idx >= B_ * COUT * HW) return;
    int w  = idx & 127;
    int h  = (idx >> 7) & 127;
    int oc = (idx >> 14) & 63;
    int b  = idx >> 20;
    float s = 0.f;
    for (int c = 0; c < CIN; ++c)
        for (int ky = 0; ky < 3; ++ky) {
            int y = h + ky - 1;
            if ((unsigned)y >= (unsigned)H_) continue;
            for (int kx = 0; kx < 3; ++kx) {
                int x = w + kx - 1;
                if ((unsigned)x >= (unsigned)W_) continue;
                s += in[((size_t)(b * CIN + c) * H_ + y) * W_ + x] *
                     wt[(((size_t)oc * CIN + c) * 3 + ky) * 3 + kx];
            }
        }
    out[idx] = s;
}

extern "C" void kernel_launch(void* const* d_in, const int* in_sizes, int n_in,
                              void* d_out, int out_size, void* d_ws, size_t ws_size,
                              hipStream_t stream) {
    const float* in = (const float*)d_in[0];
    const float* wt = (const float*)d_in[1];
    float* out = (float*)d_out;

    size_t Wp_bytes = (size_t)COUT * CIN * 9 * 2;   // 36,864

    if (ws_size >= Wp_bytes) {
        ushort* Wp = (ushort*)d_ws;
        prep_w_kernel<<<(COUT * CIN * 9 + 255) / 256, 256, 0, stream>>>(wt, Wp);
        conv_fused_kernel<<<B_ * (H_ / T_), 256, 0, stream>>>(in, Wp, out);
    } else {
        int total = B_ * COUT * HW;
        conv_naive_kernel<<<(total + 255) / 256, 256, 0, stream>>>(in, wt, out);
    }
}

// Round 16
// 45.548 us; speedup vs baseline: 1.1152x; 1.0296x over previous
//
#include <hip/hip_runtime.h>
#include <hip/hip_bf16.h>
#include <stdint.h>

typedef short bf16x8 __attribute__((ext_vector_type(8)));
typedef float f32x4  __attribute__((ext_vector_type(4)));

#define B_   32
#define CIN  32
#define COUT 64
#define H_   128
#define W_   128
#define HW   (H_ * W_)
#define T_   2            // output rows per block
#define RROWS 4           // staged input rows = T_+2
#define PXW  130          // padded width
#define SCW  68           // scratch row stride in words (16B-aligned, 2-way banks)

// s_waitcnt imm: vmcnt=63, expcnt=7, lgkmcnt=0  -> wait LDS only, NOT stores
#define WAIT_LGKM0() __builtin_amdgcn_s_waitcnt(0xC07F)

static __device__ __forceinline__ ushort f2bf(float v) {
    __hip_bfloat16 h = __float2bfloat16(v);
    return __builtin_bit_cast(ushort, h);
}

// ---------------------------------------------------------------------------
// Weight pack: [Cout][Cin][3][3] fp32 -> bf16 A-fragment order
// Wp[tap][ocg][lane][j] = W[ocg*16 + (lane&15)][8*(lane>>4)+j][ky][kx]
// ---------------------------------------------------------------------------
__global__ void prep_w_kernel(const float* __restrict__ wt, ushort* __restrict__ Wp) {
    int p = blockIdx.x * blockDim.x + threadIdx.x;
    if (p >= COUT * CIN * 9) return;  // 18432
    int j    = p & 7;
    int lane = (p >> 3) & 63;
    int g    = (p >> 9) & 3;
    int tap  = p >> 11;
    int oc   = g * 16 + (lane & 15);
    int cin  = (lane >> 4) * 8 + j;
    int ky   = tap / 3;
    int kx   = tap % 3;
    Wp[p] = f2bf(wt[(((size_t)oc * CIN + cin) * 3 + ky) * 3 + kx]);
}

// ---------------------------------------------------------------------------
// R15 structure with a VECTORIZED, ISSUE-FIRST stage phase.
// Stage: 256 units = (row r[4] x px-quad q[32] x ch-half h[2]); each thread
// issues 16 dwordx4 loads (4 px x 16 ch, 64 VGPRs in flight, no dependent
// ops between issues) -> one wait -> cvt -> 8 swizzled ds_write_b128.
// Old stage serialized ~65 scalar loads at full latency per thread (R14
// arithmetic: ~440 cy/load); this pays ~1 latency total per wave.
// Compute + full-line nontemporal epilogue unchanged from the 46.3us best.
// ---------------------------------------------------------------------------
__global__ __launch_bounds__(256, 3) void conv_fused_kernel(
    const float* __restrict__ in, const ushort* __restrict__ Wp,
    float* __restrict__ out) {
    __shared__ ushort lds[RROWS * PXW * 32];     // 33,280 B
    __shared__ float  scr[4][16 * SCW];          // 17,408 B (per-wave scratch)

    int hw_blk  = blockIdx.x;
    int logical = (hw_blk & 7) * 256 + (hw_blk >> 3);   // grid = 2048 = 8*256
    int b   = logical >> 6;          // /64
    int h0  = (logical & 63) * T_;
    int tid = threadIdx.x;

    // ---- stage: unit = (r, q, h); 16 dwordx4 issued back-to-back ----
    {
        int h_ = tid & 1;                 // ch half: ch 16h..16h+15
        int q_ = (tid >> 1) & 31;         // px quad: px = 1+4q..1+4q+3
        int r_ = tid >> 6;                // padded row (one per wave)
        int gy = h0 + r_ - 1;
        bool rowok = (gy >= 0 && gy < H_);
        int gy_e = rowok ? gy : 0;
        const float* srcb = in + (size_t)b * CIN * HW + (size_t)gy_e * W_ + 4 * q_;

        f32x4 fv[16];
#pragma unroll
        for (int k = 0; k < 16; ++k)
            fv[k] = *(const f32x4*)(srcb + (size_t)(16 * h_ + k) * HW);

        // pad columns px=0,129 zeroed by threads 0..7 (while loads fly)
        if (tid < 8) {
            int r  = tid >> 1;
            int px = (tid & 1) ? (PXW - 1) : 0;
            uint32_t colbase = (uint32_t)(r * PXW + px) * 64u;
            uint32_t sw = (((uint32_t)px >> 1) & 3u) << 4;
            bf16x8 z = (bf16x8)0;
#pragma unroll
            for (int s = 0; s < 4; ++s)
                *(bf16x8*)((char*)lds + colbase + ((((uint32_t)s) << 4) ^ sw)) = z;
        }

        // cvt + swizzled writes; off-order rotated by q for bank spread
#pragma unroll
        for (int oi = 0; oi < 4; ++oi) {
            int off = (oi + q_) & 3;
            int px  = 1 + 4 * q_ + off;
            uint32_t colbase = (uint32_t)(r_ * PXW + px) * 64u;
            uint32_t sw = (((uint32_t)px >> 1) & 3u) << 4;
#pragma unroll
            for (int s = 0; s < 2; ++s) {
                bf16x8 w;
#pragma unroll
                for (int j = 0; j < 8; ++j)
                    w[j] = rowok ? (short)f2bf(fv[8 * s + j][off]) : (short)0;
                uint32_t slot = (uint32_t)(2 * h_ + s) << 4;
                *(bf16x8*)((char*)lds + colbase + (slot ^ sw)) = w;
            }
        }
    }
    __syncthreads();

    // ---- compute: wave = (row = wid>>1, px half = wid&1), 64 oc x 64 px ----
    int wid  = tid >> 6;
    int lane = tid & 63;
    int llo  = lane & 15;
    int lhi  = lane >> 4;
    int row  = wid >> 1;            // 0..1
    int px0  = (wid & 1) * 64;
    int h    = h0 + row;

    f32x4 acc[4][4];
#pragma unroll
    for (int g = 0; g < 4; ++g)
#pragma unroll
        for (int nf = 0; nf < 4; ++nf) {
            acc[g][nf][0] = 0.f; acc[g][nf][1] = 0.f;
            acc[g][nf][2] = 0.f; acc[g][nf][3] = 0.f;
        }

#pragma unroll
    for (int tap = 0; tap < 9; ++tap) {
        int dy = tap / 3;
        int dx = tap % 3;
        int rbase = (row + dy) * PXW;
        bf16x8 Af[4];
#pragma unroll
        for (int g = 0; g < 4; ++g)
            Af[g] = *(const bf16x8*)(Wp + ((size_t)(tap * 4 + g) * 64 + lane) * 8);
#pragma unroll
        for (int nf = 0; nf < 4; ++nf) {
            int px = px0 + nf * 16 + llo + dx;
            uint32_t byte = (uint32_t)(rbase + px) * 64u +
                            (((uint32_t)lhi << 4) ^ ((((uint32_t)px >> 1) & 3u) << 4));
            bf16x8 Bf = *(const bf16x8*)((const char*)lds + byte);
#pragma unroll
            for (int g = 0; g < 4; ++g)
                acc[g][nf] = __builtin_amdgcn_mfma_f32_16x16x32_bf16(Af[g], Bf, acc[g][nf], 0, 0, 0);
        }
    }

    // ---- epilogue: per-wave LDS transpose -> full-line vector nt stores --
    float* myscr = &scr[wid][0];
    float* obase = out + (size_t)b * COUT * HW + (size_t)h * W_ + px0;
#pragma unroll
    for (int g = 0; g < 4; ++g) {
#pragma unroll
        for (int nf = 0; nf < 4; ++nf)
#pragma unroll
            for (int r = 0; r < 4; ++r)
                myscr[(lhi * 4 + r) * SCW + nf * 16 + llo] = acc[g][nf][r];
        WAIT_LGKM0();                    // scratch writes visible (LDS only)
#pragma unroll
        for (int j = 0; j < 4; ++j) {
            int ocp = j * 4 + lhi;       // 0..15
            f32x4 vv = *(const f32x4*)(myscr + ocp * SCW + llo * 4);
            int oc = g * 16 + ocp;
            f32x4* dst = (f32x4*)(obase + (size_t)oc * HW + llo * 4);
            __builtin_nontemporal_store(vv, dst);   // one dwordx4 nt
        }
        WAIT_LGKM0();                    // LDS reads done before scratch overwrite
    }
}

// ---------------------------------------------------------------------------
// Fallback: naive fp32 direct conv (only if workspace is too small for Wp)
// ---------------------------------------------------------------------------
__global__ void conv_naive_kernel(const float* __restrict__ in,
                                  const float* __restrict__ wt,
                                  float* __restrict__ out) {
    int idx = blockIdx.x * blockDim.x + threadIdx.x;
    if (idx >= B_ * COUT * HW) return;
    int w  = idx & 127;
    int h  = (idx >> 7) & 127;
    int oc = (idx >> 14) & 63;
    int b  = idx >> 20;
    float s = 0.f;
    for (int c = 0; c < CIN; ++c)
        for (int ky = 0; ky < 3; ++ky) {
            int y = h + ky - 1;
            if ((unsigned)y >= (unsigned)H_) continue;
            for (int kx = 0; kx < 3; ++kx) {
                int x = w + kx - 1;
                if ((unsigned)x >= (unsigned)W_) continue;
                s += in[((size_t)(b * CIN + c) * H_ + y) * W_ + x] *
                     wt[(((size_t)oc * CIN + c) * 3 + ky) * 3 + kx];
            }
        }
    out[idx] = s;
}

extern "C" void kernel_launch(void* const* d_in, const int* in_sizes, int n_in,
                              void* d_out, int out_size, void* d_ws, size_t ws_size,
                              hipStream_t stream) {
    const float* in = (const float*)d_in[0];
    const float* wt = (const float*)d_in[1];
    float* out = (float*)d_out;

    size_t Wp_bytes = (size_t)COUT * CIN * 9 * 2;   // 36,864

    if (ws_size >= Wp_bytes) {
        ushort* Wp = (ushort*)d_ws;
        prep_w_kernel<<<(COUT * CIN * 9 + 255) / 256, 256, 0, stream>>>(wt, Wp);
        conv_fused_kernel<<<B_ * (H_ / T_), 256, 0, stream>>>(in, Wp, out);
    } else {
        int total = B_ * COUT * HW;
        conv_naive_kernel<<<(total + 255) / 256, 256, 0, stream>>>(in, wt, out);
    }
}